// Round 1
// baseline (138.617 us; speedup 1.0000x reference)
//
#include <hip/hip_runtime.h>
#include <math.h>

// Problem constants
#define NPIX   65536      // 64*32*32 pixels
#define NELEM  655360     // 64*10*32*32 elements of z
#define NCODE  1024
#define HW     1024       // 32*32
#define CSTRIDE 1024      // stride between channels in z (h*w)
#define BSTRIDE 10240     // stride between batches in z (c*h*w)

// d_out layout (floats):
//   [0, 655360)          z_q_out  (sign(z), same b,c,h,w layout as z)
//   [655360]             loss
//   [655361]             commitment_loss
//   [655362]             entropy_loss
//   [655363]             per_sample_entropy
//   [655364]             avg_entropy
//   [655365, 720901)     min_encoding_indices (as float), layout [b,h,w]
//
// d_ws layout (floats): [0]=commit_sum, [1]=sum over pixels of (sum_n p log p),
//                       [2 .. 2+1024) = hist (sum over pixels of probs_n)

__global__ void k_sign_commit(const float* __restrict__ z,
                              float* __restrict__ out,
                              float* __restrict__ ws) {
    int tid = blockIdx.x * blockDim.x + threadIdx.x;
    int stride = gridDim.x * blockDim.x;
    float local = 0.f;
    for (int i = tid; i < NELEM; i += stride) {
        float x = z[i];
        float h = (x > 0.f) ? 1.f : -1.f;
        out[i] = h;
        float d = h - x;
        local = fmaf(d, d, local);
    }
    __shared__ float red[256];
    red[threadIdx.x] = local;
    __syncthreads();
    for (int s = 128; s > 0; s >>= 1) {
        if (threadIdx.x < s) red[threadIdx.x] += red[threadIdx.x + s];
        __syncthreads();
    }
    if (threadIdx.x == 0) atomicAdd(&ws[0], red[0]);
}

__global__ void __launch_bounds__(256)
k_pixel(const float* __restrict__ z,
        float* __restrict__ out_idx,
        float* __restrict__ ws) {
    __shared__ float hist[NCODE];
    for (int i = threadIdx.x; i < NCODE; i += 256) hist[i] = 0.f;
    __syncthreads();

    int p = blockIdx.x * 256 + threadIdx.x;   // pixel id: b*1024 + h*32 + w
    int b = p >> 10;
    int hw = p & 1023;
    const float* zp = z + b * BSTRIDE + hw;

    float v[10];
#pragma unroll
    for (int c = 0; c < 10; ++c) v[c] = zp[c * CSTRIDE];

    // bit-packed index
    int idx = 0;
#pragma unroll
    for (int c = 0; c < 10; ++c) idx |= (v[c] > 0.f) ? (1 << c) : 0;
    out_idx[p] = (float)idx;

    // logits: l_n = 400*S_n - 200*T ; shifted t_n = l_n - l_max, l_max = 200*A
    float T = 0.f, A = 0.f;
#pragma unroll
    for (int c = 0; c < 10; ++c) { T += v[c]; A += fabsf(v[c]); }
    float C0 = -200.f * T - 200.f * A;

    // tlo[lo] = 400*subset_sum(v[0..4], lo) + C0   (static-indexed -> registers)
    float tlo[32];
#pragma unroll
    for (int lo = 0; lo < 32; ++lo) {
        float s = 0.f;
#pragma unroll
        for (int c = 0; c < 5; ++c)
            if (lo & (1 << c)) s += v[c];
        tlo[lo] = fmaf(400.f, s, C0);
    }

    // pass 1: Z = sum exp(t), U = sum exp(t)*t
    float Z = 0.f, U = 0.f;
    for (int hi = 0; hi < 32; ++hi) {
        float shi = 0.f;
#pragma unroll
        for (int c = 0; c < 5; ++c)
            shi += (hi & (1 << c)) ? v[5 + c] : 0.f;
        float thi = 400.f * shi;
#pragma unroll
        for (int lo = 0; lo < 32; ++lo) {
            float t = thi + tlo[lo];
            if (t > -87.f) {           // else exp underflows to 0 anyway
                float e = __expf(t);
                Z += e;
                U = fmaf(e, t, U);
            }
        }
    }
    float invZ = 1.f / Z;
    float logZ = logf(Z);
    float plogp = U * invZ - logZ;     // sum_n p_n log p_n   (<= 0)

    // pass 2: accumulate probs into per-block histogram (avg_probs numerator)
    for (int hi = 0; hi < 32; ++hi) {
        float shi = 0.f;
#pragma unroll
        for (int c = 0; c < 5; ++c)
            shi += (hi & (1 << c)) ? v[5 + c] : 0.f;
        float thi = 400.f * shi;
#pragma unroll
        for (int lo = 0; lo < 32; ++lo) {
            float t = thi + tlo[lo];
            if (t > -30.f) {           // p < 1e-13 contributes nothing vs ~1e-3 bins
                float pr = __expf(t) * invZ;
                atomicAdd(&hist[(hi << 5) | lo], pr);
            }
        }
    }

    // reduce per-sample entropy contribution across block
    __shared__ float red[256];
    red[threadIdx.x] = plogp;
    __syncthreads();
    for (int s = 128; s > 0; s >>= 1) {
        if (threadIdx.x < s) red[threadIdx.x] += red[threadIdx.x + s];
        __syncthreads();
    }
    if (threadIdx.x == 0) atomicAdd(&ws[1], red[0]);

    __syncthreads();
    for (int i = threadIdx.x; i < NCODE; i += 256)
        if (hist[i] != 0.f) atomicAdd(&ws[2 + i], hist[i]);
}

__global__ void k_final(const float* __restrict__ ws, float* __restrict__ out) {
    __shared__ float red[1024];
    int t = threadIdx.x;
    float a = ws[2 + t] * (1.f / 65536.f);        // avg_probs[t]
    red[t] = -a * logf(a + 1e-5f);
    __syncthreads();
    for (int s = 512; s > 0; s >>= 1) {
        if (t < s) red[t] += red[t + s];
        __syncthreads();
    }
    if (t == 0) {
        float avg_entropy = red[0];                         // * ENT_GAMMA (1.0)
        float pse = -ws[1] * (1.f / 65536.f);               // per_sample_entropy
        float commit = 0.25f * ws[0] * (1.f / (float)NELEM);
        float ent_loss = 0.1f * (pse - avg_entropy);
        float loss = commit + ent_loss;
        out[NELEM + 0] = loss;
        out[NELEM + 1] = commit;
        out[NELEM + 2] = ent_loss;
        out[NELEM + 3] = pse;
        out[NELEM + 4] = avg_entropy;
    }
}

extern "C" void kernel_launch(void* const* d_in, const int* in_sizes, int n_in,
                              void* d_out, int out_size, void* d_ws, size_t ws_size,
                              hipStream_t stream) {
    const float* z = (const float*)d_in[0];
    float* out = (float*)d_out;
    float* ws = (float*)d_ws;

    // zero the accumulators (ws is re-poisoned before every call)
    hipMemsetAsync(ws, 0, (2 + NCODE) * sizeof(float), stream);

    k_sign_commit<<<1024, 256, 0, stream>>>(z, out, ws);
    k_pixel<<<NPIX / 256, 256, 0, stream>>>(z, out + NELEM + 5, ws);
    k_final<<<1, 1024, 0, stream>>>(ws, out);
}

// Round 2
// 82.299 us; speedup vs baseline: 1.6843x; 1.6843x over previous
//
#include <hip/hip_runtime.h>
#include <math.h>

// Problem constants
#define NPIX   65536      // 64*32*32 pixels
#define NELEM  655360     // 64*10*32*32 elements of z
#define NCODE  1024
#define CSTRIDE 1024      // stride between channels in z (h*w)
#define BSTRIDE 10240     // stride between batches in z (c*h*w)

// Any code flipping a channel with |v| > SOFT_T has exp(t) == 0 in fp32
// (t < -88 underflows), matching the reference's own fp32 softmax.
#define SOFT_T 0.22f

// d_out layout (floats):
//   [0, 655360)          z_q_out  (sign(z), b,c,h,w like z)
//   [655360..655364]     loss, commit, ent_loss, per_sample_entropy, avg_entropy
//   [655365, 720901)     min_encoding_indices (as float), [b,h,w]
//
// d_ws floats: [0]=commit_sum, [1]=sum over pixels of (sum_n p log p),
//              [2..2+1024) = hist (sum over pixels of probs_n)

__global__ void __launch_bounds__(256)
k_pixel(const float* __restrict__ z,
        float* __restrict__ zq,
        float* __restrict__ out_idx,
        float* __restrict__ ws) {
    __shared__ float hist[NCODE];
    __shared__ float s_av[256 * 11];          // stride 11: odd -> conflict-free
    __shared__ unsigned char s_ch[256 * 11];
    __shared__ float red[256];

    int tid = threadIdx.x;
    for (int i = tid; i < NCODE; i += 256) hist[i] = 0.f;
    __syncthreads();

    int p = blockIdx.x * 256 + tid;           // pixel id: b*1024 + h*32 + w
    int b = p >> 10;
    int hw = p & 1023;
    const float* zp = z + b * BSTRIDE + hw;
    float*       qp = zq + b * BSTRIDE + hw;

    float* av = &s_av[tid * 11];
    unsigned char* ch = &s_ch[tid * 11];

    int idx = 0, k = 0;
    float commit = 0.f;
#pragma unroll
    for (int c = 0; c < 10; ++c) {
        float x = zp[c * CSTRIDE];
        float h = (x > 0.f) ? 1.f : -1.f;
        qp[c * CSTRIDE] = h;                  // z_q output (sign)
        float d = h - x;
        commit = fmaf(d, d, commit);
        if (x > 0.f) idx |= (1 << c);
        float a = fabsf(x);
        if (a < SOFT_T) { av[k] = a; ch[k] = (unsigned char)c; ++k; }
    }
    out_idx[p] = (float)idx;

    int nsub = 1 << k;

    // pass 1: Z = sum exp(t), U = sum exp(t)*t over subsets of soft channels,
    // Gray-code order: each step flips one bit -> one add/sub.
    float Z = 1.f, U = 0.f, s = 0.f;          // subset 0: t=0, e=1
    int gray = 0;
    for (int m = 1; m < nsub; ++m) {
        int bit = __ffs(m) - 1;
        int bm = 1 << bit;
        gray ^= bm;
        float a = av[bit];
        s += (gray & bm) ? a : -a;
        float t = -400.f * s;
        float e = __expf(t);
        Z += e;
        U = fmaf(e, t, U);
    }
    float invZ = 1.f / Z;
    float plogp = U * invZ - logf(Z);         // sum_n p_n log p_n

    // pass 2: histogram of probs
    atomicAdd(&hist[idx], invZ);              // subset 0
    gray = 0; s = 0.f;
    int cmask = 0;
    for (int m = 1; m < nsub; ++m) {
        int bit = __ffs(m) - 1;
        int bm = 1 << bit;
        gray ^= bm;
        cmask ^= (1 << ch[bit]);
        float a = av[bit];
        s += (gray & bm) ? a : -a;
        float e = __expf(-400.f * s);
        atomicAdd(&hist[idx ^ cmask], e * invZ);
    }

    // block-reduce plogp and commit
    red[tid] = plogp;
    __syncthreads();
    for (int st = 128; st > 0; st >>= 1) {
        if (tid < st) red[tid] += red[tid + st];
        __syncthreads();
    }
    if (tid == 0) atomicAdd(&ws[1], red[0]);
    __syncthreads();
    red[tid] = commit;
    __syncthreads();
    for (int st = 128; st > 0; st >>= 1) {
        if (tid < st) red[tid] += red[tid + st];
        __syncthreads();
    }
    if (tid == 0) atomicAdd(&ws[0], red[0]);

    __syncthreads();
    for (int i = tid; i < NCODE; i += 256)
        if (hist[i] != 0.f) atomicAdd(&ws[2 + i], hist[i]);
}

__global__ void k_final(const float* __restrict__ ws, float* __restrict__ out) {
    __shared__ float red[1024];
    int t = threadIdx.x;
    float a = ws[2 + t] * (1.f / 65536.f);    // avg_probs[t]
    red[t] = -a * logf(a + 1e-5f);
    __syncthreads();
    for (int s = 512; s > 0; s >>= 1) {
        if (t < s) red[t] += red[t + s];
        __syncthreads();
    }
    if (t == 0) {
        float avg_entropy = red[0];                     // * ENT_GAMMA (1.0)
        float pse = -ws[1] * (1.f / 65536.f);           // per_sample_entropy
        float commit = 0.25f * ws[0] * (1.f / (float)NELEM);
        float ent_loss = 0.1f * (pse - avg_entropy);
        out[NELEM + 0] = commit + ent_loss;             // loss
        out[NELEM + 1] = commit;
        out[NELEM + 2] = ent_loss;
        out[NELEM + 3] = pse;
        out[NELEM + 4] = avg_entropy;
    }
}

extern "C" void kernel_launch(void* const* d_in, const int* in_sizes, int n_in,
                              void* d_out, int out_size, void* d_ws, size_t ws_size,
                              hipStream_t stream) {
    const float* z = (const float*)d_in[0];
    float* out = (float*)d_out;
    float* ws = (float*)d_ws;

    hipMemsetAsync(ws, 0, (2 + NCODE) * sizeof(float), stream);
    k_pixel<<<NPIX / 256, 256, 0, stream>>>(z, out, out + NELEM + 5, ws);
    k_final<<<1, 1024, 0, stream>>>(ws, out);
}